// Round 2
// baseline (323.574 us; speedup 1.0000x reference)
//
#include <hip/hip_runtime.h>

constexpr float IMG_SIZE = 448.0f;
constexpr float GSZ = 64.0f;           // IMG_SIZE / GRID_NUM
constexpr float LAMBDA_COORD = 5.0f;
constexpr float LAMBDA_NOOBJ = 0.1f;
constexpr float EPSF = 1e-12f;

// Faithful port of reference _iou (including the y1_t = cy_t + w_t/2 typo).
// All scalar args -> guaranteed register allocation, no scratch.
__device__ __forceinline__ float iou_one(float b0, float b1, float b2, float b3,
                                         float tx, float ty, float tw, float th,
                                         float gj, float gi) {
    float cx_p = b0 * GSZ + gj * GSZ;
    float cy_p = b1 * GSZ + gi * GSZ;
    float w_p  = b2 * IMG_SIZE;
    float h_p  = b3 * IMG_SIZE;
    float x0p = cx_p - 0.5f * w_p, x1p = cx_p + 0.5f * w_p;
    float y0p = cy_p - 0.5f * h_p, y1p = cy_p + 0.5f * h_p;

    float cx_t = tx * GSZ + gj * GSZ;
    float cy_t = ty * GSZ + gi * GSZ;
    float w_t  = tw * IMG_SIZE;
    float h_t  = th * IMG_SIZE;
    float x0t = cx_t - 0.5f * w_t, x1t = cx_t + 0.5f * w_t;
    float y0t = cy_t - 0.5f * h_t;
    float y1t = cy_t + 0.5f * w_t;   // faithful typo: w_t, not h_t

    float ux0 = fmaxf(x0p, x0t), ux1 = fminf(x1p, x1t);
    float uy0 = fmaxf(y0p, y0t), uy1 = fminf(y1p, y1t);
    bool valid = (ux0 < ux1) && (uy0 < uy1);
    float au = (ux1 - ux0) * (uy1 - uy0);
    float ap = (x1p - x0p) * (y1p - y0p);
    float at = (x1t - x0t) * (y1t - y0t);
    float res = au / (ap + at - au + EPSF);
    return valid ? res : 0.0f;
}

__device__ __forceinline__ float cell_loss(float p0, float p1, float p2, float p3, float p4,
                                           float p5, float p6, float p7, float p8, float p9,
                                           float t0, float t1, float t2, float t3, float t4,
                                           float gj, float gi) {
    float iou0 = iou_one(p0, p1, p2, p3, t0, t1, t2, t3, gj, gi);
    float iou1 = iou_one(p5, p6, p7, p8, t0, t1, t2, t3, gj, gi);
    bool obj = (t4 == 1.0f);
    bool ch0 = iou0 > iou1;

    // obj branch (predicated selects, no divergent memory ops)
    float cp = ch0 ? p4 : p9;
    float ct = ch0 ? iou0 : iou1;
    float d  = cp - ct;
    float loss_obj = d * d;
    float dx = (ch0 ? p0 : p5) - t0;
    float dy = (ch0 ? p1 : p6) - t1;
    loss_obj += LAMBDA_COORD * (dx * dx + dy * dy);
    float wp = fmaxf(ch0 ? p2 : p7, EPSF);
    float hp = fmaxf(ch0 ? p3 : p8, EPSF);
    float wt = fmaxf(t2, EPSF);
    float ht = fmaxf(t3, EPSF);
    float dw = sqrtf(wp) - sqrtf(wt);
    float dh = sqrtf(hp) - sqrtf(ht);
    loss_obj += LAMBDA_COORD * (dw * dw + dh * dh);

    float loss_noobj = LAMBDA_NOOBJ * (p4 * p4 + p9 * p9);
    return obj ? loss_obj : loss_noobj;
}

__global__ __launch_bounds__(256)
void yolo_loss_kernel(const float* __restrict__ y_pre,
                      const float* __restrict__ y_true,
                      float* __restrict__ out,
                      int cells, float invB) {
    int c = blockIdx.x * blockDim.x + threadIdx.x;
    float local = 0.0f;

    if (c < cells) {
        const float* p = y_pre + (size_t)c * 10;   // 40 B / cell, 8-byte aligned
        float2 p01 = *(const float2*)(p + 0);
        float2 p23 = *(const float2*)(p + 2);
        float2 p45 = *(const float2*)(p + 4);
        float2 p67 = *(const float2*)(p + 6);
        float2 p89 = *(const float2*)(p + 8);

        const float* t = y_true + (size_t)c * 5;   // 20 B / cell
        float t0 = t[0], t1 = t[1], t2 = t[2], t3 = t[3], t4 = t[4];

        int rc = c % 49;                 // cell index within the 7x7 grid
        float gi = (float)(rc / 7);
        float gj = (float)(rc % 7);

        local = cell_loss(p01.x, p01.y, p23.x, p23.y, p45.x,
                          p45.y, p67.x, p67.y, p89.x, p89.y,
                          t0, t1, t2, t3, t4, gj, gi);
    }

    // Wave-64 shuffle reduce.
    #pragma unroll
    for (int off = 32; off > 0; off >>= 1)
        local += __shfl_down(local, off, 64);

    __shared__ float smem[4];            // 256 threads = 4 waves
    int lane = threadIdx.x & 63;
    int wid  = threadIdx.x >> 6;
    if (lane == 0) smem[wid] = local;
    __syncthreads();
    if (threadIdx.x == 0) {
        float s = smem[0] + smem[1] + smem[2] + smem[3];
        atomicAdd(out, s * invB);
    }
}

extern "C" void kernel_launch(void* const* d_in, const int* in_sizes, int n_in,
                              void* d_out, int out_size, void* d_ws, size_t ws_size,
                              hipStream_t stream) {
    const float* y_pre  = (const float*)d_in[0];
    const float* y_true = (const float*)d_in[1];
    float* out = (float*)d_out;

    int cells = in_sizes[0] / 10;        // B * 7 * 7
    int B     = cells / 49;
    float invB = 1.0f / (float)B;

    hipMemsetAsync(out, 0, sizeof(float), stream);  // d_out is poisoned to 0xAA

    int blocks = (cells + 255) / 256;
    yolo_loss_kernel<<<blocks, 256, 0, stream>>>(y_pre, y_true, out, cells, invB);
}

// Round 3
// 262.453 us; speedup vs baseline: 1.2329x; 1.2329x over previous
//
#include <hip/hip_runtime.h>

constexpr float IMG_SIZE = 448.0f;
constexpr float GSZ = 64.0f;           // IMG_SIZE / GRID_NUM
constexpr float LAMBDA_COORD = 5.0f;
constexpr float LAMBDA_NOOBJ = 0.1f;
constexpr float EPSF = 1e-12f;

#define TPB 256          // threads per block
#define CPB 512          // cells per block (2 per thread)

// Faithful port of reference _iou (including the y1_t = cy_t + w_t/2 typo).
__device__ __forceinline__ float iou_one(float b0, float b1, float b2, float b3,
                                         float tx, float ty, float tw, float th,
                                         float gj, float gi) {
    float cx_p = b0 * GSZ + gj * GSZ;
    float cy_p = b1 * GSZ + gi * GSZ;
    float w_p  = b2 * IMG_SIZE;
    float h_p  = b3 * IMG_SIZE;
    float x0p = cx_p - 0.5f * w_p, x1p = cx_p + 0.5f * w_p;
    float y0p = cy_p - 0.5f * h_p, y1p = cy_p + 0.5f * h_p;

    float cx_t = tx * GSZ + gj * GSZ;
    float cy_t = ty * GSZ + gi * GSZ;
    float w_t  = tw * IMG_SIZE;
    float h_t  = th * IMG_SIZE;
    float x0t = cx_t - 0.5f * w_t, x1t = cx_t + 0.5f * w_t;
    float y0t = cy_t - 0.5f * h_t;
    float y1t = cy_t + 0.5f * w_t;   // faithful typo: w_t, not h_t

    float ux0 = fmaxf(x0p, x0t), ux1 = fminf(x1p, x1t);
    float uy0 = fmaxf(y0p, y0t), uy1 = fminf(y1p, y1t);
    bool valid = (ux0 < ux1) && (uy0 < uy1);
    float au = (ux1 - ux0) * (uy1 - uy0);
    float ap = (x1p - x0p) * (y1p - y0p);
    float at = (x1t - x0t) * (y1t - y0t);
    float res = au / (ap + at - au + EPSF);
    return valid ? res : 0.0f;
}

__device__ __forceinline__ float cell_loss(float p0, float p1, float p2, float p3, float p4,
                                           float p5, float p6, float p7, float p8, float p9,
                                           float t0, float t1, float t2, float t3, float t4,
                                           float gj, float gi) {
    float iou0 = iou_one(p0, p1, p2, p3, t0, t1, t2, t3, gj, gi);
    float iou1 = iou_one(p5, p6, p7, p8, t0, t1, t2, t3, gj, gi);
    bool obj = (t4 == 1.0f);
    bool ch0 = iou0 > iou1;

    float cp = ch0 ? p4 : p9;
    float ct = ch0 ? iou0 : iou1;
    float d  = cp - ct;
    float loss_obj = d * d;
    float dx = (ch0 ? p0 : p5) - t0;
    float dy = (ch0 ? p1 : p6) - t1;
    loss_obj += LAMBDA_COORD * (dx * dx + dy * dy);
    float wp = fmaxf(ch0 ? p2 : p7, EPSF);
    float hp = fmaxf(ch0 ? p3 : p8, EPSF);
    float wt = fmaxf(t2, EPSF);
    float ht = fmaxf(t3, EPSF);
    float dw = sqrtf(wp) - sqrtf(wt);
    float dh = sqrtf(hp) - sqrtf(ht);
    loss_obj += LAMBDA_COORD * (dw * dw + dh * dh);

    float loss_noobj = LAMBDA_NOOBJ * (p4 * p4 + p9 * p9);
    return obj ? loss_obj : loss_noobj;
}

__global__ __launch_bounds__(TPB)
void yolo_loss_kernel(const float4* __restrict__ y_pre4,
                      const float4* __restrict__ y_true4,
                      float* __restrict__ out,
                      int cells, float invB) {
    // LDS tiles: CPB cells -> 20480 + 10240 = 30720 B / block
    __shared__ float sp[CPB * 10];
    __shared__ float st[CPB * 5];

    int tid = threadIdx.x;
    int cell0 = blockIdx.x * CPB;

    // Stage y_pre: CPB*10/4 = 1280 float4, lane-contiguous (fully coalesced).
    int base_p4 = cell0 * 10 / 4;            // CPB*10 divisible by 4
    int lim_p4  = cells * 10 / 4;            // cells*10 divisible by 4 (cells mult of 2)
    #pragma unroll
    for (int k = 0; k < 5; ++k) {
        int i = tid + k * TPB;               // 0..1279
        int g = base_p4 + i;
        if (g < lim_p4) *(float4*)&sp[i * 4] = y_pre4[g];
    }
    // Stage y_true: CPB*5/4 = 640 float4.
    int base_t4 = cell0 * 5 / 4;             // CPB*5 divisible by 4
    int lim_t4  = (cells * 5) / 4;
    #pragma unroll
    for (int k = 0; k < 3; ++k) {
        int i = tid + k * TPB;
        if (i < CPB * 5 / 4) {
            int g = base_t4 + i;
            if (g < lim_t4) *(float4*)&st[i * 4] = y_true4[g];
        }
    }
    __syncthreads();

    float local = 0.0f;
    #pragma unroll
    for (int k = 0; k < 2; ++k) {
        int ci = tid + k * TPB;              // cell within block tile
        int c  = cell0 + ci;
        if (c < cells) {
            const float* p = &sp[ci * 10];
            const float* t = &st[ci * 5];
            int rc = c % 49;
            float gi = (float)(rc / 7);
            float gj = (float)(rc % 7);
            local += cell_loss(p[0], p[1], p[2], p[3], p[4],
                               p[5], p[6], p[7], p[8], p[9],
                               t[0], t[1], t[2], t[3], t[4], gj, gi);
        }
    }

    // Wave-64 shuffle reduce, then cross-wave via LDS, one atomic per block.
    #pragma unroll
    for (int off = 32; off > 0; off >>= 1)
        local += __shfl_down(local, off, 64);

    __shared__ float smem[TPB / 64];
    int lane = tid & 63;
    int wid  = tid >> 6;
    if (lane == 0) smem[wid] = local;
    __syncthreads();
    if (tid == 0) {
        float s = 0.0f;
        #pragma unroll
        for (int w = 0; w < TPB / 64; ++w) s += smem[w];
        atomicAdd(out, s * invB);
    }
}

extern "C" void kernel_launch(void* const* d_in, const int* in_sizes, int n_in,
                              void* d_out, int out_size, void* d_ws, size_t ws_size,
                              hipStream_t stream) {
    const float4* y_pre4  = (const float4*)d_in[0];
    const float4* y_true4 = (const float4*)d_in[1];
    float* out = (float*)d_out;

    int cells = in_sizes[0] / 10;            // B * 7 * 7
    int B     = cells / 49;
    float invB = 1.0f / (float)B;

    hipMemsetAsync(out, 0, sizeof(float), stream);  // d_out poisoned to 0xAA

    int blocks = (cells + CPB - 1) / CPB;
    yolo_loss_kernel<<<blocks, TPB, 0, stream>>>(y_pre4, y_true4, out, cells, invB);
}

// Round 4
// 227.544 us; speedup vs baseline: 1.4220x; 1.1534x over previous
//
#include <hip/hip_runtime.h>

constexpr float IMG_SIZE = 448.0f;
constexpr float GSZ = 64.0f;           // IMG_SIZE / GRID_NUM
constexpr float LAMBDA_COORD = 5.0f;
constexpr float LAMBDA_NOOBJ = 0.1f;
constexpr float EPSF = 1e-12f;

#define TPB 256          // threads per block
#define CPB 512          // cells per tile (2 per thread)
#define MAXBLK 1280      // 5 blocks/CU * 256 CUs, matches LDS-limited occupancy

// Faithful port of reference _iou (including the y1_t = cy_t + w_t/2 typo).
__device__ __forceinline__ float iou_one(float b0, float b1, float b2, float b3,
                                         float tx, float ty, float tw, float th,
                                         float gj, float gi) {
    float cx_p = b0 * GSZ + gj * GSZ;
    float cy_p = b1 * GSZ + gi * GSZ;
    float w_p  = b2 * IMG_SIZE;
    float h_p  = b3 * IMG_SIZE;
    float x0p = cx_p - 0.5f * w_p, x1p = cx_p + 0.5f * w_p;
    float y0p = cy_p - 0.5f * h_p, y1p = cy_p + 0.5f * h_p;

    float cx_t = tx * GSZ + gj * GSZ;
    float cy_t = ty * GSZ + gi * GSZ;
    float w_t  = tw * IMG_SIZE;
    float h_t  = th * IMG_SIZE;
    float x0t = cx_t - 0.5f * w_t, x1t = cx_t + 0.5f * w_t;
    float y0t = cy_t - 0.5f * h_t;
    float y1t = cy_t + 0.5f * w_t;   // faithful typo: w_t, not h_t

    float ux0 = fmaxf(x0p, x0t), ux1 = fminf(x1p, x1t);
    float uy0 = fmaxf(y0p, y0t), uy1 = fminf(y1p, y1t);
    bool valid = (ux0 < ux1) && (uy0 < uy1);
    float au = (ux1 - ux0) * (uy1 - uy0);
    float ap = (x1p - x0p) * (y1p - y0p);
    float at = (x1t - x0t) * (y1t - y0t);
    float res = au / (ap + at - au + EPSF);
    return valid ? res : 0.0f;
}

__device__ __forceinline__ float cell_loss(float p0, float p1, float p2, float p3, float p4,
                                           float p5, float p6, float p7, float p8, float p9,
                                           float t0, float t1, float t2, float t3, float t4,
                                           float gj, float gi) {
    float iou0 = iou_one(p0, p1, p2, p3, t0, t1, t2, t3, gj, gi);
    float iou1 = iou_one(p5, p6, p7, p8, t0, t1, t2, t3, gj, gi);
    bool obj = (t4 == 1.0f);
    bool ch0 = iou0 > iou1;

    float cp = ch0 ? p4 : p9;
    float ct = ch0 ? iou0 : iou1;
    float d  = cp - ct;
    float loss_obj = d * d;
    float dx = (ch0 ? p0 : p5) - t0;
    float dy = (ch0 ? p1 : p6) - t1;
    loss_obj += LAMBDA_COORD * (dx * dx + dy * dy);
    float wp = fmaxf(ch0 ? p2 : p7, EPSF);
    float hp = fmaxf(ch0 ? p3 : p8, EPSF);
    float wt = fmaxf(t2, EPSF);
    float ht = fmaxf(t3, EPSF);
    float dw = sqrtf(wp) - sqrtf(wt);
    float dh = sqrtf(hp) - sqrtf(ht);
    loss_obj += LAMBDA_COORD * (dw * dw + dh * dh);

    float loss_noobj = LAMBDA_NOOBJ * (p4 * p4 + p9 * p9);
    return obj ? loss_obj : loss_noobj;
}

__global__ __launch_bounds__(TPB)
void yolo_loss_kernel(const float4* __restrict__ y_pre4,
                      const float4* __restrict__ y_true4,
                      float* __restrict__ partials,
                      int cells, int ntiles) {
    __shared__ float sp[CPB * 10];   // 20480 B
    __shared__ float st[CPB * 5];    // 10240 B

    int tid = threadIdx.x;
    int lim_p4 = cells * 10 / 4;
    int lim_t4 = cells * 5 / 4;

    float acc = 0.0f;

    for (int tile = blockIdx.x; tile < ntiles; tile += gridDim.x) {
        int cell0 = tile * CPB;

        // Stage y_pre: 1280 float4, lane-contiguous (fully coalesced).
        int base_p4 = cell0 * 10 / 4;
        #pragma unroll
        for (int k = 0; k < 5; ++k) {
            int i = tid + k * TPB;
            int g = base_p4 + i;
            if (g < lim_p4) *(float4*)&sp[i * 4] = y_pre4[g];
        }
        // Stage y_true: 640 float4.
        int base_t4 = cell0 * 5 / 4;
        #pragma unroll
        for (int k = 0; k < 3; ++k) {
            int i = tid + k * TPB;
            if (i < CPB * 5 / 4) {
                int g = base_t4 + i;
                if (g < lim_t4) *(float4*)&st[i * 4] = y_true4[g];
            }
        }
        __syncthreads();

        #pragma unroll
        for (int k = 0; k < 2; ++k) {
            int ci = tid + k * TPB;
            int c  = cell0 + ci;
            if (c < cells) {
                const float* p = &sp[ci * 10];
                const float* t = &st[ci * 5];
                int rc = c % 49;
                float gi = (float)(rc / 7);
                float gj = (float)(rc % 7);
                acc += cell_loss(p[0], p[1], p[2], p[3], p[4],
                                 p[5], p[6], p[7], p[8], p[9],
                                 t[0], t[1], t[2], t[3], t[4], gj, gi);
            }
        }
        __syncthreads();   // protect LDS before next tile's staging
    }

    // Wave-64 shuffle reduce, then cross-wave via LDS; ONE plain store per
    // block (no contended atomic — that serialized ~10 ns/block in R1-R3).
    #pragma unroll
    for (int off = 32; off > 0; off >>= 1)
        acc += __shfl_down(acc, off, 64);

    __shared__ float smem[TPB / 64];
    int lane = tid & 63;
    int wid  = tid >> 6;
    if (lane == 0) smem[wid] = acc;
    __syncthreads();
    if (tid == 0) {
        float s = 0.0f;
        #pragma unroll
        for (int w = 0; w < TPB / 64; ++w) s += smem[w];
        partials[blockIdx.x] = s;
    }
}

__global__ __launch_bounds__(TPB)
void reduce_kernel(const float* __restrict__ partials,
                   float* __restrict__ out, int n, float invB) {
    int tid = threadIdx.x;
    float s = 0.0f;
    for (int i = tid; i < n; i += TPB) s += partials[i];

    #pragma unroll
    for (int off = 32; off > 0; off >>= 1)
        s += __shfl_down(s, off, 64);

    __shared__ float smem[TPB / 64];
    int lane = tid & 63;
    int wid  = tid >> 6;
    if (lane == 0) smem[wid] = s;
    __syncthreads();
    if (tid == 0) {
        float tot = 0.0f;
        #pragma unroll
        for (int w = 0; w < TPB / 64; ++w) tot += smem[w];
        out[0] = tot * invB;
    }
}

extern "C" void kernel_launch(void* const* d_in, const int* in_sizes, int n_in,
                              void* d_out, int out_size, void* d_ws, size_t ws_size,
                              hipStream_t stream) {
    const float4* y_pre4  = (const float4*)d_in[0];
    const float4* y_true4 = (const float4*)d_in[1];
    float* out = (float*)d_out;
    float* partials = (float*)d_ws;

    int cells = in_sizes[0] / 10;            // B * 7 * 7
    int B     = cells / 49;
    float invB = 1.0f / (float)B;

    int ntiles  = (cells + CPB - 1) / CPB;
    int nblocks = ntiles < MAXBLK ? ntiles : MAXBLK;

    yolo_loss_kernel<<<nblocks, TPB, 0, stream>>>(y_pre4, y_true4, partials,
                                                  cells, ntiles);
    reduce_kernel<<<1, TPB, 0, stream>>>(partials, out, nblocks, invB);
}